// Round 22
// baseline (245.851 us; speedup 1.0000x reference)
//
#include <hip/hip_runtime.h>
#include <hip/hip_bf16.h>

#define Bn 16
#define Nn 4096
#define LOG2E 1.44269504088896f

#if __has_builtin(__builtin_amdgcn_exp2f)
#define EXP2(x) __builtin_amdgcn_exp2f(x)
#else
#define EXP2(x) __expf((x) * 0.69314718055994531f)
#endif

typedef __attribute__((ext_vector_type(8))) short bf16x8;
typedef __attribute__((ext_vector_type(16))) float f32x16;

static __device__ __forceinline__ unsigned short f2bf(float f) {
    union { float f; unsigned int u; } v; v.f = f;
    return (unsigned short)((v.u + 0x7fffu + ((v.u >> 16) & 1u)) >> 16);
}
static __device__ __forceinline__ int cvtpk(float lo, float hi) {
    int d; asm("v_cvt_pk_bf16_f32 %0, %1, %2" : "=v"(d) : "v"(lo), "v"(hi)); return d;
}
static __device__ __forceinline__ bf16x8 mkfrag(int a, int b, int c, int d) {
    union { int i[4]; bf16x8 v; } u; u.i[0]=a; u.i[1]=b; u.i[2]=c; u.i[3]=d; return u.v;
}

// ---------------- Stage 1: 1x1 convs -> fragment-packed Qf/Kf/Vf (bf16) -------------
// (byte-identical to round 21, which passed)
__global__ __launch_bounds__(512) void qkv_kernel(
    const float* __restrict__ x,
    const float* __restrict__ w1,
    const float* __restrict__ w2,
    const float* __restrict__ w3,
    uint4* __restrict__ Qf,
    uint4* __restrict__ Kf,
    uint4* __restrict__ Vf)
{
    __shared__ __align__(16) unsigned char smem[64 * 264 * 2];  // 33792 B
    float* wlds = (float*)smem;                                  // 128 rows x 64 c
    unsigned short (*vtile)[264] = (unsigned short (*)[264])smem;

    const int t = threadIdx.x;
    {   // stage w1|w2|w3 -> wlds (2048 float4, 4 per thread)
        float4* wd = (float4*)wlds;
        wd[t]        = ((const float4*)w1)[t];
        wd[512 + t]  = ((const float4*)w2)[t];
        wd[1024 + t] = ((const float4*)w3)[t];
        wd[1536 + t] = ((const float4*)w3)[512 + t];
    }

    const int lane = t & 63;
    const int w8   = t >> 6;                 // row-group: 0-1 K, 2-3 Q, 4-7 V
    const int b    = blockIdx.x >> 4;        // 16 blocks per batch
    const int nb   = (blockIdx.x & 15) << 8; // 256 positions per block
    const float* xb = x + ((size_t)b << 18) + nb + lane;

    const float* wbase = wlds + w8 * 1024;   // 16 rows x 64 c per group
    const float scl = (w8 < 2) ? LOG2E : 1.0f;

    float acc[4][16];
    #pragma unroll
    for (int pp = 0; pp < 4; ++pp)
        #pragma unroll
        for (int i = 0; i < 16; ++i) acc[pp][i] = 0.f;

    __syncthreads();   // wlds ready

    #pragma unroll 1
    for (int ch = 0; ch < 8; ++ch) {         // c-chunks of 8; c-order stays 0..63
        float xr[4][8];
        #pragma unroll
        for (int pp = 0; pp < 4; ++pp)
            #pragma unroll
            for (int c = 0; c < 8; ++c)
                xr[pp][c] = xb[((size_t)(ch * 8 + c) << 12) + pp * 64];
        #pragma unroll
        for (int i = 0; i < 16; ++i) {
            const float* wr = wbase + i * 64 + ch * 8;   // wave-uniform LDS addr
            const float4 wa = *(const float4*)wr;
            const float4 wb = *(const float4*)(wr + 4);
            #pragma unroll
            for (int pp = 0; pp < 4; ++pp) {
                float a = acc[pp][i];
                a = fmaf(wa.x, xr[pp][0], a);
                a = fmaf(wa.y, xr[pp][1], a);
                a = fmaf(wa.z, xr[pp][2], a);
                a = fmaf(wa.w, xr[pp][3], a);
                a = fmaf(wb.x, xr[pp][4], a);
                a = fmaf(wb.y, xr[pp][5], a);
                a = fmaf(wb.z, xr[pp][6], a);
                a = fmaf(wb.w, xr[pp][7], a);
                acc[pp][i] = a;
            }
        }
    }
    #pragma unroll
    for (int pp = 0; pp < 4; ++pp)
        #pragma unroll
        for (int i = 0; i < 16; ++i) acc[pp][i] *= scl;   // x1.0 exact for Q/V

    __syncthreads();   // all wlds reads done; smem may be reused as vtile

    if (w8 < 4) {
        uint4* dstb = (w8 < 2) ? Kf : Qf;
        const int dt = w8 & 1;               // rows dt*16..dt*16+15
        #pragma unroll
        for (int pp = 0; pp < 4; ++pp) {
            const float* ac = acc[pp];
            const int pos = pp * 64 + lane;  // 0..255 in block
            const int ntile = ((blockIdx.x & 15) << 3) + (pos >> 5);
            uint4* dst = dstb + (((size_t)b * 128 + ntile) * 2) * 64;
            uint4 u0, u1;
            u0.x = (unsigned)f2bf(ac[0])  | ((unsigned)f2bf(ac[1])  << 16);
            u0.y = (unsigned)f2bf(ac[2])  | ((unsigned)f2bf(ac[3])  << 16);
            u0.z = (unsigned)f2bf(ac[4])  | ((unsigned)f2bf(ac[5])  << 16);
            u0.w = (unsigned)f2bf(ac[6])  | ((unsigned)f2bf(ac[7])  << 16);
            u1.x = (unsigned)f2bf(ac[8])  | ((unsigned)f2bf(ac[9])  << 16);
            u1.y = (unsigned)f2bf(ac[10]) | ((unsigned)f2bf(ac[11]) << 16);
            u1.z = (unsigned)f2bf(ac[12]) | ((unsigned)f2bf(ac[13]) << 16);
            u1.w = (unsigned)f2bf(ac[14]) | ((unsigned)f2bf(ac[15]) << 16);
            dst[(size_t)dt * 64 + (pos & 31)]      = u0;
            dst[(size_t)dt * 64 + 32 + (pos & 31)] = u1;
        }
    } else {
        const int rbase = (w8 - 4) * 16;
        #pragma unroll
        for (int i = 0; i < 16; ++i)
            #pragma unroll
            for (int pp = 0; pp < 4; ++pp)
                vtile[rbase + i][pp * 64 + lane] = f2bf(acc[pp][i]);
    }
    __syncthreads();

    // Vf scatter with permuted k-order gather
    #pragma unroll
    for (int i = 0; i < 4; ++i) {
        const int slot = t * 4 + i;          // [kvt:3][ct:1][jt:1][l:6]
        const int l   = slot & 63;
        const int jt  = (slot >> 6) & 1;
        const int ct  = (slot >> 7) & 1;
        const int kvt = slot >> 8;           // 0..7 local kv tile
        const int row  = ct * 32 + (l & 31);
        const int base = kvt * 32 + jt * 16 + ((l >> 5) << 2);
        const uint2 lo = *(const uint2*)&vtile[row][base];      // k = 4h + 0..3
        const uint2 hi = *(const uint2*)&vtile[row][base + 8];  // k = 4h + 8..11
        const int kvtg = ((blockIdx.x & 15) << 3) + kvt;
        Vf[((((size_t)b * 128 + kvtg) * 2 + ct) * 2 + jt) * 64 + l] =
            make_uint4(lo.x, lo.y, hi.x, hi.y);
    }
}

// ---------------- Stage 2: flash attention, 4-wave block, 2q x 2-KV-half ----------
// grid 1024 x 256 thr (4 waves). Wave wv: q-tile = qp*2 + (wv&1), KV half = wv>>1
// (64 iters). r9-proven skeleton (3-chunk sp[] staging at 256 thr, VGPR-safe) +
// r21-proven per-tile math. 4 blocks/CU = 4 independent barrier domains (2x r21)
// for MFMA/VALU cross-wave overlap. Additive merge through dead kvbuf.
__global__ __launch_bounds__(256) void attn_kernel(
    const bf16x8* __restrict__ Qf,
    const bf16x8* __restrict__ Kf,
    const bf16x8* __restrict__ Vf,
    const float* __restrict__ x,
    const float* __restrict__ gamma,
    float* __restrict__ out)
{
    __shared__ __align__(16) unsigned char kvbuf[2 * 2 * 6144]; // [stream][buf][6144] = 24 KB

    const int t    = threadIdx.x;
    const int lane = t & 63;
    const int wv   = t >> 6;
    const int id   = blockIdx.x;
    const int b    = 2 * (id & 7) + ((id >> 3) >> 6);   // XCD-chunked batch map
    const int qp   = (id >> 3) & 63;                    // q-pair 0..63
    const int q    = wv & 1;
    const int h    = wv >> 1;                           // KV half
    const int qt   = qp * 2 + q;                        // 0..127

    const bf16x8* Qp = Qf + ((size_t)(b * 128 + qt) * 2) * 64;
    const bf16x8  qf0 = Qp[lane];
    const bf16x8  qf1 = Qp[64 + lane];
    const bf16x8* Kp = Kf + (size_t)b * 128 * 2 * 64;
    const bf16x8* Vp = Vf + (size_t)b * 128 * 4 * 64;

    // all-ones bf16 A-fragment (1.0bf16 = 0x3F80)
    const bf16x8 ones = mkfrag(0x3F803F80, 0x3F803F80, 0x3F803F80, 0x3F803F80);

    // staging: 768 chunks/iter = 2 streams x 6 slots [K0,K1,V00,V01,V10,V11] x 64 lanes
    // thread t stages chunks {t, t+256, t+512} (constant (stream,slot,lane) per thread)
    const bf16x8* sp[3];
    int strp[3], dof[3];
    #pragma unroll
    for (int k = 0; k < 3; ++k) {
        const int c = t + k * 256;
        const int s = c / 384;            // stream (KV half)
        const int r = c % 384;
        const int slot = r >> 6;
        const int ln = r & 63;
        dof[k] = s * 12288 + r * 16;      // + buf*6144 at store time
        if (slot < 2) { sp[k] = Kp + ((size_t)(s * 64) * 2 + slot) * 64 + ln;       strp[k] = 128; }
        else          { sp[k] = Vp + ((size_t)(s * 64) * 4 + (slot - 2)) * 64 + ln; strp[k] = 256; }
    }

    // prologue: stage tile 0 of both streams -> buf 0
    #pragma unroll
    for (int k = 0; k < 3; ++k) {
        *(uint4*)(kvbuf + dof[k]) = *(const uint4*)sp[k];
        sp[k] += strp[k];
    }
    __syncthreads();

    f32x16 o0 = {}, o1 = {}, lsum = {};

    for (int i = 0; i < 64; ++i) {
        // issue next-tile loads early (latency hidden under compute)
        uint4 st[3];
        if (i < 63) {
            #pragma unroll
            for (int k = 0; k < 3; ++k) {
                st[k] = *(const uint4*)sp[k];
                sp[k] += strp[k];
            }
        }

        const bf16x8* bc = (const bf16x8*)(kvbuf + h * 12288 + (i & 1) * 6144);
        const bf16x8 kf0 = bc[lane];
        const bf16x8 kf1 = bc[64 + lane];
        const bf16x8 v00 = bc[128 + lane];
        const bf16x8 v01 = bc[192 + lane];
        const bf16x8 v10 = bc[256 + lane];
        const bf16x8 v11 = bc[320 + lane];

        // S^T tile (exp2 domain): rows = kpos(32), cols = q; D=32 -> 2 chained MFMAs
        f32x16 s;
        {
            f32x16 z = {};
            __builtin_amdgcn_s_setprio(1);
            s = __builtin_amdgcn_mfma_f32_32x32x16_bf16(kf0, qf0, z, 0, 0, 0);
            s = __builtin_amdgcn_mfma_f32_32x32x16_bf16(kf1, qf1, s, 0, 0, 0);
            __builtin_amdgcn_s_setprio(0);
        }

        // P = 2^S directly — no max tracking, K pre-scaled; 16 independent TRANS ops
        float p[16];
        #pragma unroll
        for (int j = 0; j < 16; ++j) p[j] = EXP2(s[j]);

        // P -> B-frag directly (V k-order permuted at pack time; no lane exchange)
        const bf16x8 pf0 = mkfrag(cvtpk(p[0],  p[1]),  cvtpk(p[2],  p[3]),
                                  cvtpk(p[4],  p[5]),  cvtpk(p[6],  p[7]));
        const bf16x8 pf1 = mkfrag(cvtpk(p[8],  p[9]),  cvtpk(p[10], p[11]),
                                  cvtpk(p[12], p[13]), cvtpk(p[14], p[15]));

        // O^T += V^T x P^T ; l += ones x P^T (full 32-k column sum, every lane)
        __builtin_amdgcn_s_setprio(1);
        o0 = __builtin_amdgcn_mfma_f32_32x32x16_bf16(v00, pf0, o0, 0, 0, 0);
        o0 = __builtin_amdgcn_mfma_f32_32x32x16_bf16(v01, pf1, o0, 0, 0, 0);
        o1 = __builtin_amdgcn_mfma_f32_32x32x16_bf16(v10, pf0, o1, 0, 0, 0);
        o1 = __builtin_amdgcn_mfma_f32_32x32x16_bf16(v11, pf1, o1, 0, 0, 0);
        lsum = __builtin_amdgcn_mfma_f32_32x32x16_bf16(ones, pf0, lsum, 0, 0, 0);
        lsum = __builtin_amdgcn_mfma_f32_32x32x16_bf16(ones, pf1, lsum, 0, 0, 0);
        __builtin_amdgcn_s_setprio(0);

        // write next tile into the other buffer (safe: nobody reads it this iter)
        if (i < 63) {
            const int bo = ((i + 1) & 1) * 6144;
            #pragma unroll
            for (int k = 0; k < 3; ++k)
                *(uint4*)(kvbuf + dof[k] + bo) = st[k];
        }
        __syncthreads();
    }

    float lacc = lsum[0];   // all rows/halves identical: full column sum for q = lane&31

    // ---- merge halves (pure addition) through dead kvbuf ----
    float* const mbase = (float*)kvbuf;
    if (h == 1) {
        float* mg = mbase + ((size_t)(q * 64 + lane)) * 33;
        #pragma unroll
        for (int j = 0; j < 16; ++j) { mg[j] = o0[j]; mg[16 + j] = o1[j]; }
        mg[32] = lacc;
    }
    __syncthreads();
    if (h == 0) {
        const float* mg = mbase + ((size_t)(q * 64 + lane)) * 33;
        #pragma unroll
        for (int j = 0; j < 16; ++j) { o0[j] += mg[j]; o1[j] += mg[16 + j]; }
        lacc += mg[32];

        // ---- epilogue: out[b][c][n] = g * O^T[c][q]/l + x[b][c][n], n = q ----
        const float g = gamma[0];
        const float rl = 1.0f / lacc;    // lacc already the full row sum
        const int n = qt * 32 + (lane & 31);
        const int hi1 = lane >> 5;
        #pragma unroll
        for (int r = 0; r < 16; ++r) {
            const int c0r = (r & 3) + 8 * (r >> 2) + 4 * hi1;
            {
                const size_t idx = (((size_t)b * 64 + c0r) << 12) + n;
                out[idx] = g * o0[r] * rl + x[idx];
            }
            {
                const size_t idx = (((size_t)b * 64 + 32 + c0r) << 12) + n;
                out[idx] = g * o1[r] * rl + x[idx];
            }
        }
    }
}

extern "C" void kernel_launch(void* const* d_in, const int* in_sizes, int n_in,
                              void* d_out, int out_size, void* d_ws, size_t ws_size,
                              hipStream_t stream) {
    const float* x     = (const float*)d_in[0];
    const float* w1    = (const float*)d_in[1];
    const float* w2    = (const float*)d_in[2];
    const float* w3    = (const float*)d_in[3];
    const float* gamma = (const float*)d_in[4];
    float* out = (float*)d_out;

    uint4* Qf = (uint4*)d_ws;                        // 4 MB
    uint4* Kf = Qf + (size_t)Bn * 128 * 2 * 64;      // 4 MB
    uint4* Vf = Kf + (size_t)Bn * 128 * 2 * 64;      // 8 MB

    qkv_kernel<<<256, 512, 0, stream>>>(x, w1, w2, w3, Qf, Kf, Vf);
    attn_kernel<<<1024, 256, 0, stream>>>((const bf16x8*)Qf, (const bf16x8*)Kf,
                                          (const bf16x8*)Vf, x, gamma, out);
}

// Round 23
// 97.145 us; speedup vs baseline: 2.5308x; 2.5308x over previous
//
#include <hip/hip_runtime.h>
#include <hip/hip_bf16.h>

#define Bn 16
#define Nn 4096
#define LOG2E 1.44269504088896f

#if __has_builtin(__builtin_amdgcn_exp2f)
#define EXP2(x) __builtin_amdgcn_exp2f(x)
#else
#define EXP2(x) __expf((x) * 0.69314718055994531f)
#endif

typedef __attribute__((ext_vector_type(8))) short bf16x8;
typedef __attribute__((ext_vector_type(16))) float f32x16;

static __device__ __forceinline__ unsigned short f2bf(float f) {
    union { float f; unsigned int u; } v; v.f = f;
    return (unsigned short)((v.u + 0x7fffu + ((v.u >> 16) & 1u)) >> 16);
}
static __device__ __forceinline__ int cvtpk(float lo, float hi) {
    int d; asm("v_cvt_pk_bf16_f32 %0, %1, %2" : "=v"(d) : "v"(lo), "v"(hi)); return d;
}
static __device__ __forceinline__ bf16x8 mkfrag(int a, int b, int c, int d) {
    union { int i[4]; bf16x8 v; } u; u.i[0]=a; u.i[1]=b; u.i[2]=c; u.i[3]=d; return u.v;
}

// ---------------- Stage 1: 1x1 convs -> fragment-packed Qf/Kf/Vf (bf16) -------------
// (byte-identical to round 21, which passed)
__global__ __launch_bounds__(512) void qkv_kernel(
    const float* __restrict__ x,
    const float* __restrict__ w1,
    const float* __restrict__ w2,
    const float* __restrict__ w3,
    uint4* __restrict__ Qf,
    uint4* __restrict__ Kf,
    uint4* __restrict__ Vf)
{
    __shared__ __align__(16) unsigned char smem[64 * 264 * 2];  // 33792 B
    float* wlds = (float*)smem;                                  // 128 rows x 64 c
    unsigned short (*vtile)[264] = (unsigned short (*)[264])smem;

    const int t = threadIdx.x;
    {   // stage w1|w2|w3 -> wlds (2048 float4, 4 per thread)
        float4* wd = (float4*)wlds;
        wd[t]        = ((const float4*)w1)[t];
        wd[512 + t]  = ((const float4*)w2)[t];
        wd[1024 + t] = ((const float4*)w3)[t];
        wd[1536 + t] = ((const float4*)w3)[512 + t];
    }

    const int lane = t & 63;
    const int w8   = t >> 6;                 // row-group: 0-1 K, 2-3 Q, 4-7 V
    const int b    = blockIdx.x >> 4;        // 16 blocks per batch
    const int nb   = (blockIdx.x & 15) << 8; // 256 positions per block
    const float* xb = x + ((size_t)b << 18) + nb + lane;

    const float* wbase = wlds + w8 * 1024;   // 16 rows x 64 c per group
    const float scl = (w8 < 2) ? LOG2E : 1.0f;

    float acc[4][16];
    #pragma unroll
    for (int pp = 0; pp < 4; ++pp)
        #pragma unroll
        for (int i = 0; i < 16; ++i) acc[pp][i] = 0.f;

    __syncthreads();   // wlds ready

    #pragma unroll 1
    for (int ch = 0; ch < 8; ++ch) {         // c-chunks of 8; c-order stays 0..63
        float xr[4][8];
        #pragma unroll
        for (int pp = 0; pp < 4; ++pp)
            #pragma unroll
            for (int c = 0; c < 8; ++c)
                xr[pp][c] = xb[((size_t)(ch * 8 + c) << 12) + pp * 64];
        #pragma unroll
        for (int i = 0; i < 16; ++i) {
            const float* wr = wbase + i * 64 + ch * 8;   // wave-uniform LDS addr
            const float4 wa = *(const float4*)wr;
            const float4 wb = *(const float4*)(wr + 4);
            #pragma unroll
            for (int pp = 0; pp < 4; ++pp) {
                float a = acc[pp][i];
                a = fmaf(wa.x, xr[pp][0], a);
                a = fmaf(wa.y, xr[pp][1], a);
                a = fmaf(wa.z, xr[pp][2], a);
                a = fmaf(wa.w, xr[pp][3], a);
                a = fmaf(wb.x, xr[pp][4], a);
                a = fmaf(wb.y, xr[pp][5], a);
                a = fmaf(wb.z, xr[pp][6], a);
                a = fmaf(wb.w, xr[pp][7], a);
                acc[pp][i] = a;
            }
        }
    }
    #pragma unroll
    for (int pp = 0; pp < 4; ++pp)
        #pragma unroll
        for (int i = 0; i < 16; ++i) acc[pp][i] *= scl;   // x1.0 exact for Q/V

    __syncthreads();   // all wlds reads done; smem may be reused as vtile

    if (w8 < 4) {
        uint4* dstb = (w8 < 2) ? Kf : Qf;
        const int dt = w8 & 1;               // rows dt*16..dt*16+15
        #pragma unroll
        for (int pp = 0; pp < 4; ++pp) {
            const float* ac = acc[pp];
            const int pos = pp * 64 + lane;  // 0..255 in block
            const int ntile = ((blockIdx.x & 15) << 3) + (pos >> 5);
            uint4* dst = dstb + (((size_t)b * 128 + ntile) * 2) * 64;
            uint4 u0, u1;
            u0.x = (unsigned)f2bf(ac[0])  | ((unsigned)f2bf(ac[1])  << 16);
            u0.y = (unsigned)f2bf(ac[2])  | ((unsigned)f2bf(ac[3])  << 16);
            u0.z = (unsigned)f2bf(ac[4])  | ((unsigned)f2bf(ac[5])  << 16);
            u0.w = (unsigned)f2bf(ac[6])  | ((unsigned)f2bf(ac[7])  << 16);
            u1.x = (unsigned)f2bf(ac[8])  | ((unsigned)f2bf(ac[9])  << 16);
            u1.y = (unsigned)f2bf(ac[10]) | ((unsigned)f2bf(ac[11]) << 16);
            u1.z = (unsigned)f2bf(ac[12]) | ((unsigned)f2bf(ac[13]) << 16);
            u1.w = (unsigned)f2bf(ac[14]) | ((unsigned)f2bf(ac[15]) << 16);
            dst[(size_t)dt * 64 + (pos & 31)]      = u0;
            dst[(size_t)dt * 64 + 32 + (pos & 31)] = u1;
        }
    } else {
        const int rbase = (w8 - 4) * 16;
        #pragma unroll
        for (int i = 0; i < 16; ++i)
            #pragma unroll
            for (int pp = 0; pp < 4; ++pp)
                vtile[rbase + i][pp * 64 + lane] = f2bf(acc[pp][i]);
    }
    __syncthreads();

    // Vf scatter with permuted k-order gather
    #pragma unroll
    for (int i = 0; i < 4; ++i) {
        const int slot = t * 4 + i;          // [kvt:3][ct:1][jt:1][l:6]
        const int l   = slot & 63;
        const int jt  = (slot >> 6) & 1;
        const int ct  = (slot >> 7) & 1;
        const int kvt = slot >> 8;           // 0..7 local kv tile
        const int row  = ct * 32 + (l & 31);
        const int base = kvt * 32 + jt * 16 + ((l >> 5) << 2);
        const uint2 lo = *(const uint2*)&vtile[row][base];      // k = 4h + 0..3
        const uint2 hi = *(const uint2*)&vtile[row][base + 8];  // k = 4h + 8..11
        const int kvtg = ((blockIdx.x & 15) << 3) + kvt;
        Vf[((((size_t)b * 128 + kvtg) * 2 + ct) * 2 + jt) * 64 + l] =
            make_uint4(lo.x, lo.y, hi.x, hi.y);
    }
}

// ---------------- Stage 2: flash attention, 8-wave block, 2-way KV split ----------
// (round-21 structure/math/staging byte-identical. ONE change: merge routed
//  through the DEAD kvbuf in 2 phases instead of a separate 38 KB mgbuf ->
//  LDS 61 KB -> 24.5 KB -> 4 blocks/CU = 32 waves/CU, 2x barrier domains.)
__global__ __launch_bounds__(512) void attn_kernel(
    const bf16x8* __restrict__ Qf,
    const bf16x8* __restrict__ Kf,
    const bf16x8* __restrict__ Vf,
    const float* __restrict__ x,
    const float* __restrict__ gamma,
    float* __restrict__ out)
{
    __shared__ __align__(16) unsigned char kvbuf[2 * 12288]; // [stream][buf][6144] = 24.5 KB

    const int t    = threadIdx.x;
    const int lane = t & 63;
    const int wv   = t >> 6;
    const int id   = blockIdx.x;
    const int b    = 2 * (id & 7) + ((id >> 3) >> 5);   // XCD-chunked batch map
    const int qg   = (id >> 3) & 31;
    const int qt   = qg * 4 + (wv & 3);                 // 0..127
    const int h    = wv >> 2;                           // KV half for this wave

    const bf16x8* Qp = Qf + ((size_t)(b * 128 + qt) * 2) * 64;
    const bf16x8  qf0 = Qp[lane];
    const bf16x8  qf1 = Qp[64 + lane];
    const bf16x8* Kp = Kf + (size_t)b * 128 * 2 * 64;
    const bf16x8* Vp = Vf + (size_t)b * 128 * 4 * 64;

    // all-ones bf16 A-fragment (1.0bf16 = 0x3F80); ones matrix is layout-proof
    const bf16x8 ones = mkfrag(0x3F803F80, 0x3F803F80, 0x3F803F80, 0x3F803F80);

    // staging: 768 chunks/iter = 2 streams x 6 slots [K0,K1,V00,V01,V10,V11] x 64 lanes
    const int s0  = (t >= 384);          // stream of chunk t
    const int r0  = t - s0 * 384;
    const int sl0 = r0 >> 6;
    const int l0  = r0 & 63;
    const int dof0 = s0 * 12288 + r0 * 16;
    const bool two = (t < 256);
    const int r1  = t + 128;             // chunk 512+t -> stream 1, r = t+128
    const int sl1 = r1 >> 6;             // 2..5 (V slots)
    const int l1  = t & 63;
    const int dof1 = 12288 + r1 * 16;

    // strength-reduced source pointers (identical addresses to the SRC_OF chain)
    const bf16x8* sp0 = (sl0 < 2)
        ? (Kp + ((size_t)(s0 * 64) * 2 + sl0) * 64 + l0)
        : (Vp + ((size_t)(s0 * 64) * 4 + (sl0 - 2)) * 64 + l0);
    const int str0 = (sl0 < 2) ? 128 : 256;          // bf16x8 elems per tile step
    const bf16x8* sp1 = Vp + ((size_t)64 * 4 + (sl1 - 2)) * 64 + l1;  // stream 1, V slots

    // prologue: stage tile 0 of both streams -> buf 0
    {
        *(uint4*)(kvbuf + dof0) = *(const uint4*)sp0;
        sp0 += str0;
        if (two) {
            *(uint4*)(kvbuf + dof1) = *(const uint4*)sp1;
            sp1 += 256;
        }
    }
    __syncthreads();

    f32x16 o0 = {}, o1 = {}, lsum = {};

    for (int i = 0; i < 64; ++i) {
        // issue next-tile loads early (latency hidden under compute)
        uint4 st0, st1;
        if (i < 63) {
            st0 = *(const uint4*)sp0; sp0 += str0;
            if (two) { st1 = *(const uint4*)sp1; sp1 += 256; }
        }

        const bf16x8* bc = (const bf16x8*)(kvbuf + h * 12288 + (i & 1) * 6144);
        const bf16x8 kf0 = bc[lane];
        const bf16x8 kf1 = bc[64 + lane];
        const bf16x8 v00 = bc[128 + lane];
        const bf16x8 v01 = bc[192 + lane];
        const bf16x8 v10 = bc[256 + lane];
        const bf16x8 v11 = bc[320 + lane];

        // S^T tile (exp2 domain): rows = kpos(32), cols = q; D=32 -> 2 chained MFMAs
        f32x16 s;
        {
            f32x16 z = {};
            __builtin_amdgcn_s_setprio(1);
            s = __builtin_amdgcn_mfma_f32_32x32x16_bf16(kf0, qf0, z, 0, 0, 0);
            s = __builtin_amdgcn_mfma_f32_32x32x16_bf16(kf1, qf1, s, 0, 0, 0);
            __builtin_amdgcn_s_setprio(0);
        }

        // P = 2^S directly — no max tracking, K pre-scaled; 16 independent TRANS ops
        float p[16];
        #pragma unroll
        for (int j = 0; j < 16; ++j) p[j] = EXP2(s[j]);

        // P -> B-frag directly (V k-order permuted at pack time; no lane exchange)
        const bf16x8 pf0 = mkfrag(cvtpk(p[0],  p[1]),  cvtpk(p[2],  p[3]),
                                  cvtpk(p[4],  p[5]),  cvtpk(p[6],  p[7]));
        const bf16x8 pf1 = mkfrag(cvtpk(p[8],  p[9]),  cvtpk(p[10], p[11]),
                                  cvtpk(p[12], p[13]), cvtpk(p[14], p[15]));

        // O^T += V^T x P^T ; l += ones x P^T (full 32-k column sum, every lane)
        __builtin_amdgcn_s_setprio(1);
        o0 = __builtin_amdgcn_mfma_f32_32x32x16_bf16(v00, pf0, o0, 0, 0, 0);
        o0 = __builtin_amdgcn_mfma_f32_32x32x16_bf16(v01, pf1, o0, 0, 0, 0);
        o1 = __builtin_amdgcn_mfma_f32_32x32x16_bf16(v10, pf0, o1, 0, 0, 0);
        o1 = __builtin_amdgcn_mfma_f32_32x32x16_bf16(v11, pf1, o1, 0, 0, 0);
        lsum = __builtin_amdgcn_mfma_f32_32x32x16_bf16(ones, pf0, lsum, 0, 0, 0);
        lsum = __builtin_amdgcn_mfma_f32_32x32x16_bf16(ones, pf1, lsum, 0, 0, 0);
        __builtin_amdgcn_s_setprio(0);

        // write next tile into the other buffer (safe: nobody reads it this iter)
        if (i < 63) {
            const int bo = ((i + 1) & 1) * 6144;
            *(uint4*)(kvbuf + dof0 + bo) = st0;
            if (two) *(uint4*)(kvbuf + dof1 + bo) = st1;
        }
        __syncthreads();
    }

    float lacc = lsum[0];   // all rows/halves identical: full column sum for q = lane&31

    // ---- merge halves (pure addition) through the DEAD kvbuf, 2 phases ----
    // pair (wv, wv+4); 2 waves publish per phase: 2 x 64 x 33 floats = 16.9 KB <= 24.5 KB
    float* const mbase = (float*)kvbuf;
    if (wv == 4 || wv == 5) {
        float* mg = mbase + ((size_t)((wv - 4) * 64 + lane)) * 33;
        #pragma unroll
        for (int j = 0; j < 16; ++j) { mg[j] = o0[j]; mg[16 + j] = o1[j]; }
        mg[32] = lacc;
    }
    __syncthreads();
    if (wv < 2) {
        const float* mg = mbase + ((size_t)(wv * 64 + lane)) * 33;
        #pragma unroll
        for (int j = 0; j < 16; ++j) { o0[j] += mg[j]; o1[j] += mg[16 + j]; }
        lacc += mg[32];
    }
    __syncthreads();
    if (wv == 6 || wv == 7) {
        float* mg = mbase + ((size_t)((wv - 6) * 64 + lane)) * 33;
        #pragma unroll
        for (int j = 0; j < 16; ++j) { mg[j] = o0[j]; mg[16 + j] = o1[j]; }
        mg[32] = lacc;
    }
    __syncthreads();
    if (wv == 2 || wv == 3) {
        const float* mg = mbase + ((size_t)((wv - 2) * 64 + lane)) * 33;
        #pragma unroll
        for (int j = 0; j < 16; ++j) { o0[j] += mg[j]; o1[j] += mg[16 + j]; }
        lacc += mg[32];
    }

    if (wv < 4) {
        // ---- epilogue: out[b][c][n] = g * O^T[c][q]/l + x[b][c][n], n = q ----
        const float g = gamma[0];
        const float rl = 1.0f / lacc;    // lacc already the full row sum
        const int n = qt * 32 + (lane & 31);
        const int hi1 = lane >> 5;
        #pragma unroll
        for (int r = 0; r < 16; ++r) {
            const int c0r = (r & 3) + 8 * (r >> 2) + 4 * hi1;
            {
                const size_t idx = (((size_t)b * 64 + c0r) << 12) + n;
                out[idx] = g * o0[r] * rl + x[idx];
            }
            {
                const size_t idx = (((size_t)b * 64 + 32 + c0r) << 12) + n;
                out[idx] = g * o1[r] * rl + x[idx];
            }
        }
    }
}

extern "C" void kernel_launch(void* const* d_in, const int* in_sizes, int n_in,
                              void* d_out, int out_size, void* d_ws, size_t ws_size,
                              hipStream_t stream) {
    const float* x     = (const float*)d_in[0];
    const float* w1    = (const float*)d_in[1];
    const float* w2    = (const float*)d_in[2];
    const float* w3    = (const float*)d_in[3];
    const float* gamma = (const float*)d_in[4];
    float* out = (float*)d_out;

    uint4* Qf = (uint4*)d_ws;                        // 4 MB
    uint4* Kf = Qf + (size_t)Bn * 128 * 2 * 64;      // 4 MB
    uint4* Vf = Kf + (size_t)Bn * 128 * 2 * 64;      // 8 MB

    qkv_kernel<<<256, 512, 0, stream>>>(x, w1, w2, w3, Qf, Kf, Vf);
    attn_kernel<<<512, 512, 0, stream>>>((const bf16x8*)Qf, (const bf16x8*)Kf,
                                         (const bf16x8*)Vf, x, gamma, out);
}